// Round 9
// baseline (101.497 us; speedup 1.0000x reference)
//
#include <hip/hip_runtime.h>

#define TT 128
#define BB 512
#define DD 512
#define HH 512
#define CC 32
#define NQ 10
#define GC 128      // 4 gates * 32 centres
#define DH 1024     // D + H
#define CHUNK 8
#define NCHUNK (TT / CHUNK)
#define L2E 1.4426950408889634f

typedef __fp16 h2 __attribute__((ext_vector_type(2)));
typedef __fp16 h4 __attribute__((ext_vector_type(4)));
typedef __fp16 h8 __attribute__((ext_vector_type(8)));
typedef float f4 __attribute__((ext_vector_type(4)));

__device__ __forceinline__ float rcpf(float x) { return __builtin_amdgcn_rcpf(x); }
__device__ __forceinline__ float exp2fast(float x) {
#if __has_builtin(__builtin_amdgcn_exp2f)
    return __builtin_amdgcn_exp2f(x);
#else
    return exp2f(x);
#endif
}

__global__ __launch_bounds__(512, 2) void qlstm_kernel(
    const float* __restrict__ inputs,   // [T][B][D]
    const float* __restrict__ centres,  // [4][C][DH]
    const float* __restrict__ lin_w,    // [4][H][C]
    const float* __restrict__ lin_b,    // [4][H]
    float* __restrict__ out)            // outputs [T][B][H] | h [B][H] | c [B][H]
{
    // 72 KB total -> 2 blocks/CU. xs/cs alias into preB (dead after phase A).
    __shared__ __fp16 Klds[TT * GC];                 // 32 KB, XOR-swizzled rows
    __shared__ __align__(16) uint2 preB[8 * HH];     // 32 KB: (F f32 | IG2,O h2)
    __shared__ float blds[4 * HH];                   // 8 KB scale-folded biases

    float* csT = (float*)preB;            // [NQ][128]: 0.5*centres, transposed
    float* xsA = (float*)preB + NQ * 128; // [TT][12]:  0.5*x rows

    const int b = blockIdx.x;
    const int tid = threadIdx.x;
    const int lane = tid & 63;
    const int w = tid >> 6;       // wave id; wave w owns h in [w*64, w*64+64)
    const int q = lane >> 4;      // 0..3
    const int c16 = lane & 15;

    // ---- stage 0.5*x (row-major, pad 12) and 0.5*centres (transposed) ----
    for (int idx = tid; idx < TT * NQ; idx += 512) {
        int t = idx / NQ, d = idx - t * NQ;
        xsA[t * 12 + d] = 0.5f * inputs[((size_t)t * BB + b) * DD + d];
    }
    for (int idx = tid; idx < GC * NQ; idx += 512) {
        int gc = idx & 127, d = idx >> 7;
        csT[d * 128 + gc] = 0.5f * centres[(size_t)gc * DH + d];
    }
    for (int idx = tid; idx < 4 * HH; idx += 512) {
        int g = idx >> 9;
        float s = (g == 2) ? (2.f * L2E) : (-L2E);
        blds[idx] = s * lin_b[idx];
    }
    __syncthreads();

    // ---- B fragments (scale-folded weights): lane = (col c16, k q*8+e) ----
    h8 bfr[16];   // [g*4 + j]
    {
        const int c0 = q * 8;
        #pragma unroll
        for (int g = 0; g < 4; ++g) {
            const float s = (g == 2) ? (2.f * L2E) : (-L2E);
            #pragma unroll
            for (int j = 0; j < 4; ++j) {
                const int hcol = (w * 4 + j) * 16 + c16;
                const float* wp = lin_w + (((size_t)g * HH + hcol) * CC + c0);
                f4 lo = *(const f4*)wp;
                f4 hi = *(const f4*)(wp + 4);
                h2 p0 = __builtin_amdgcn_cvt_pkrtz(s * lo.x, s * lo.y);
                h2 p1 = __builtin_amdgcn_cvt_pkrtz(s * lo.z, s * lo.w);
                h2 p2 = __builtin_amdgcn_cvt_pkrtz(s * hi.x, s * hi.y);
                h2 p3 = __builtin_amdgcn_cvt_pkrtz(s * hi.z, s * hi.w);
                h8 bb = { p0.x, p0.y, p1.x, p1.y, p2.x, p2.y, p3.x, p3.y };
                bfr[g * 4 + j] = bb;
            }
        }
    }

    // ---- Phase A: K[t][gc] -> Klds f16 (swizzled write), f32 angles ----
    {
        const int gcq = (tid & 31) * 4;
        const int t0 = tid >> 5;
        #pragma unroll
        for (int p = 0; p < 8; ++p) {
            const int t = t0 + p * 16;
            float pr0 = 1.f, pr1 = 1.f, pr2 = 1.f, pr3 = 1.f;
            #pragma unroll
            for (int d = 0; d < NQ; ++d) {
                float xd = xsA[t * 12 + d];                   // broadcast read
                f4 cd = *(const f4*)&csT[d * 128 + gcq];      // conflict-free b128
                pr0 *= fabsf(__cosf(xd - cd.x));
                pr1 *= fabsf(__cosf(xd - cd.y));
                pr2 *= fabsf(__cosf(xd - cd.z));
                pr3 *= fabsf(__cosf(xd - cd.w));
            }
            h2 lo2 = __builtin_amdgcn_cvt_pkrtz(pr0, pr1);
            h2 hi2 = __builtin_amdgcn_cvt_pkrtz(pr2, pr3);
            h4 kk = { lo2.x, lo2.y, hi2.x, hi2.y };
            int byteo = (t * 256 + gcq * 2) ^ ((t & 7) << 4);
            *(h4*)((char*)Klds + byteo) = kk;
        }
    }
    __syncthreads();   // Klds done; xsA/csT dead; preB reuse begins below

    // ---- per 8-t chunk: MFMA + activations (parallel), then recurrence ----
    float cs2 = 0.f, hstate = 0.f;   // cs2 = 2*log2e*c
    float* op = out + (size_t)b * HH + tid;
    const int tlo = c16 & 7;         // duplicated A rows (round-7-proven)
    int aoff[4];
    #pragma unroll
    for (int g = 0; g < 4; ++g)
        aoff[g] = tlo * 256 + ((g * 64 + q * 16) ^ (tlo << 4));
    const int hcolbase = w * 64 + c16;

    for (int ct = 0; ct < NCHUNK; ++ct) {
        const char* arp = (const char*)Klds + ct * 2048;
        h8 afr[4];
        #pragma unroll
        for (int g = 0; g < 4; ++g)
            afr[g] = *(const h8*)(arp + aoff[g]);

        #pragma unroll
        for (int j = 0; j < 4; ++j) {
            const int hcol = hcolbase + j * 16;
            const float bf = blds[0 * HH + hcol];
            const float bi = blds[1 * HH + hcol];
            const float bg = blds[2 * HH + hcol];
            const float bo = blds[3 * HH + hcol];
            f4 cf = { bf, bf, bf, bf };
            f4 ci = { bi, bi, bi, bi };
            f4 cg = { bg, bg, bg, bg };
            f4 co = { bo, bo, bo, bo };
            f4 aF = __builtin_amdgcn_mfma_f32_16x16x32_f16(afr[0], bfr[0*4+j], cf, 0, 0, 0);
            f4 aI = __builtin_amdgcn_mfma_f32_16x16x32_f16(afr[1], bfr[1*4+j], ci, 0, 0, 0);
            f4 aG = __builtin_amdgcn_mfma_f32_16x16x32_f16(afr[2], bfr[2*4+j], cg, 0, 0, 0);
            f4 aO = __builtin_amdgcn_mfma_f32_16x16x32_f16(afr[3], bfr[3*4+j], co, 0, 0, 0);
            // D: col = c16 (h), row = q*4+r; rows 8-15 dup rows 0-7, q<2 writes
            if (q < 2) {
                #pragma unroll
                for (int r = 0; r < 4; ++r) {
                    float F   = rcpf(1.f + exp2fast(aF[r]));       // sigma(f)
                    float si  = rcpf(1.f + exp2fast(aI[r]));       // sigma(i)
                    float rg  = rcpf(1.f + exp2fast(aG[r]));
                    float gg2 = fmaf(-4.f * L2E, rg, 2.f * L2E);   // 2log2e*tanh(g)
                    float O   = rcpf(1.f + exp2fast(aO[r]));       // sigma(o)
                    h2 io = __builtin_amdgcn_cvt_pkrtz(si * gg2, O);
                    uint2 uu;
                    uu.x = __builtin_bit_cast(unsigned, F);        // F kept f32
                    uu.y = *(unsigned*)&io;
                    preB[(q * 4 + r) * HH + hcol] = uu;
                }
            }
        }

        // recurrence: thread = h, 8 steps, 1 ds_read_b64 each.
        // Same-wave in-order LDS; preB columns wave-private.
        #pragma unroll
        for (int s = 0; s < CHUNK; ++s) {
            uint2 vv = preB[s * HH + tid];
            float F = __builtin_bit_cast(float, vv.x);
            h2 io = *(h2*)&vv.y;
            cs2 = fmaf(F, cs2, (float)io.x);
            float th = fmaf(-2.f, rcpf(1.f + exp2fast(cs2)), 1.f);
            hstate = (float)io.y * th;
            op[(size_t)(ct * CHUNK + s) * (BB * HH)] = hstate;
        }
    }

    float* hout = out + (size_t)TT * BB * HH;
    float* cout = hout + (size_t)BB * HH;
    hout[(size_t)b * HH + tid] = hstate;
    cout[(size_t)b * HH + tid] = cs2 * 0.34657359027997264f;   // /(2*log2e)
}

extern "C" void kernel_launch(void* const* d_in, const int* in_sizes, int n_in,
                              void* d_out, int out_size, void* d_ws, size_t ws_size,
                              hipStream_t stream) {
    const float* inputs  = (const float*)d_in[0];
    const float* centres = (const float*)d_in[1];
    const float* lin_w   = (const float*)d_in[2];
    const float* lin_b   = (const float*)d_in[3];
    float* out = (float*)d_out;

    qlstm_kernel<<<dim3(BB), dim3(512), 0, stream>>>(inputs, centres, lin_w, lin_b, out);
}

// Round 10
// 93.993 us; speedup vs baseline: 1.0798x; 1.0798x over previous
//
#include <hip/hip_runtime.h>

#define TT 128
#define BB 512
#define DD 512
#define HH 512
#define CC 32
#define NQ 10
#define GC 128      // 4 gates * 32 centres
#define DH 1024     // D + H
#define CHUNK 8
#define NCHUNK (TT / CHUNK)
#define HLOC 256    // h-columns per block
#define L2E 1.4426950408889634f

typedef __fp16 h2 __attribute__((ext_vector_type(2)));
typedef __fp16 h4 __attribute__((ext_vector_type(4)));
typedef __fp16 h8 __attribute__((ext_vector_type(8)));
typedef float f4 __attribute__((ext_vector_type(4)));

__device__ __forceinline__ float rcpf(float x) { return __builtin_amdgcn_rcpf(x); }
__device__ __forceinline__ float exp2fast(float x) {
#if __has_builtin(__builtin_amdgcn_exp2f)
    return __builtin_amdgcn_exp2f(x);
#else
    return exp2f(x);
#endif
}

__global__ __launch_bounds__(256, 3) void qlstm_kernel(
    const float* __restrict__ inputs,   // [T][B][D]
    const float* __restrict__ centres,  // [4][C][DH]
    const float* __restrict__ lin_w,    // [4][H][C]
    const float* __restrict__ lin_b,    // [4][H]
    float* __restrict__ out)            // outputs [T][B][H] | h [B][H] | c [B][H]
{
    // 52 KB total -> 3 blocks/CU (12 waves/CU)
    __shared__ __fp16 Klds[TT * GC];                       // 32 KB, swizzled
    __shared__ __align__(16) unsigned preBx[CHUNK * HLOC * 2]; // 16 KB
    __shared__ float blds[4 * HLOC];                       // 4 KB folded biases

    float* csT = (float*)preBx;             // [NQ][128]: 0.5*centres (transposed)
    float* xsA = (float*)preBx + NQ * 128;  // [TT][12]:  0.5*x rows  (11 KB total)

    const int bid = blockIdx.x;
    const int b = bid >> 1;          // adjacent blocks share b -> L2 reuse of x
    const int hbase = (bid & 1) * HLOC;

    const int tid = threadIdx.x;     // 0..255
    const int lane = tid & 63;
    const int w = tid >> 6;          // wave 0..3; wave w owns local h [w*64,w*64+64)
    const int q = lane >> 4;         // 0..3
    const int c16 = lane & 15;
    const int hi = lane >> 5;        // 0: compute F,O ; 1: compute si,gg2

    // ---- stage 0.5*x (rows, pad 12), 0.5*centres (transposed), biases ----
    for (int idx = tid; idx < TT * NQ; idx += 256) {
        int t = idx / NQ, d = idx - t * NQ;
        xsA[t * 12 + d] = 0.5f * inputs[((size_t)t * BB + b) * DD + d];
    }
    for (int idx = tid; idx < GC * NQ; idx += 256) {
        int gc = idx & 127, d = idx >> 7;
        csT[d * 128 + gc] = 0.5f * centres[(size_t)gc * DH + d];
    }
    for (int idx = tid; idx < 4 * HLOC; idx += 256) {
        int g = idx >> 8, hl = idx & 255;
        float s = (g == 2) ? (2.f * L2E) : (-L2E);
        blds[idx] = s * lin_b[g * HH + hbase + hl];
    }
    __syncthreads();

    // ---- B fragments (scale-folded weights): lane = (col c16, k q*8+e) ----
    h8 bfr[16];   // [g*4 + j]
    {
        const int c0 = q * 8;
        #pragma unroll
        for (int g = 0; g < 4; ++g) {
            const float s = (g == 2) ? (2.f * L2E) : (-L2E);
            #pragma unroll
            for (int j = 0; j < 4; ++j) {
                const int hcolg = hbase + w * 64 + j * 16 + c16;
                const float* wp = lin_w + (((size_t)g * HH + hcolg) * CC + c0);
                f4 lo = *(const f4*)wp;
                f4 hif = *(const f4*)(wp + 4);
                h2 p0 = __builtin_amdgcn_cvt_pkrtz(s * lo.x, s * lo.y);
                h2 p1 = __builtin_amdgcn_cvt_pkrtz(s * lo.z, s * lo.w);
                h2 p2 = __builtin_amdgcn_cvt_pkrtz(s * hif.x, s * hif.y);
                h2 p3 = __builtin_amdgcn_cvt_pkrtz(s * hif.z, s * hif.w);
                h8 bb = { p0.x, p0.y, p1.x, p1.y, p2.x, p2.y, p3.x, p3.y };
                bfr[g * 4 + j] = bb;
            }
        }
    }

    // ---- Phase A: K[t][gc] -> Klds f16 (swizzled write), f32 angles ----
    {
        const int gcq = (tid & 31) * 4;
        const int t0 = tid >> 5;         // 0..7
        #pragma unroll
        for (int p = 0; p < 16; ++p) {
            const int t = t0 + p * 8;
            float pr0 = 1.f, pr1 = 1.f, pr2 = 1.f, pr3 = 1.f;
            #pragma unroll
            for (int d = 0; d < NQ; ++d) {
                float xd = xsA[t * 12 + d];                  // broadcast read
                f4 cd = *(const f4*)&csT[d * 128 + gcq];     // b128 read
                pr0 *= fabsf(__cosf(xd - cd.x));
                pr1 *= fabsf(__cosf(xd - cd.y));
                pr2 *= fabsf(__cosf(xd - cd.z));
                pr3 *= fabsf(__cosf(xd - cd.w));
            }
            h2 lo2 = __builtin_amdgcn_cvt_pkrtz(pr0, pr1);
            h2 hi2 = __builtin_amdgcn_cvt_pkrtz(pr2, pr3);
            h4 kk = { lo2.x, lo2.y, hi2.x, hi2.y };
            int byteo = (t * 256 + gcq * 2) ^ ((t & 7) << 4);
            *(h4*)((char*)Klds + byteo) = kk;
        }
    }
    __syncthreads();   // Klds done; xsA/csT dead; preBx reuse begins below

    // ---- per 8-t chunk: MFMA + lane-split activations, then recurrence ----
    float cs2 = 0.f, hstate = 0.f;   // cs2 = 2*log2e*c
    float* op = out + (size_t)b * HH + hbase + tid;
    const int tlo = c16 & 7;         // duplicated A rows (round-7-proven)
    int aoff[4];
    #pragma unroll
    for (int g = 0; g < 4; ++g)
        aoff[g] = tlo * 256 + ((g * 64 + q * 16) ^ (tlo << 4));
    const int hclbase = w * 64 + c16;     // local column
    const int rl0 = (q & 1) * 4;          // t-row base within chunk

    for (int ct = 0; ct < NCHUNK; ++ct) {
        const char* arp = (const char*)Klds + ct * 2048;
        h8 afr[4];
        #pragma unroll
        for (int g = 0; g < 4; ++g)
            afr[g] = *(const h8*)(arp + aoff[g]);

        #pragma unroll
        for (int j = 0; j < 4; ++j) {
            const int hcl = hclbase + j * 16;
            const float bf = blds[0 * HLOC + hcl];
            const float bi = blds[1 * HLOC + hcl];
            const float bg = blds[2 * HLOC + hcl];
            const float bo = blds[3 * HLOC + hcl];
            f4 cf = { bf, bf, bf, bf };
            f4 ci = { bi, bi, bi, bi };
            f4 cg = { bg, bg, bg, bg };
            f4 co = { bo, bo, bo, bo };
            f4 aF = __builtin_amdgcn_mfma_f32_16x16x32_f16(afr[0], bfr[0*4+j], cf, 0, 0, 0);
            f4 aI = __builtin_amdgcn_mfma_f32_16x16x32_f16(afr[1], bfr[1*4+j], ci, 0, 0, 0);
            f4 aG = __builtin_amdgcn_mfma_f32_16x16x32_f16(afr[2], bfr[2*4+j], cg, 0, 0, 0);
            f4 aO = __builtin_amdgcn_mfma_f32_16x16x32_f16(afr[3], bfr[3*4+j], co, 0, 0, 0);
            // Dup lane-pairs (q,q+2) hold identical rows: split the 4 gates.
            // lo (hi=0): e1=F, e2=O ; hi (hi=1): e1=si, e2=rg -> IG2=si*gg2.
            #pragma unroll
            for (int r = 0; r < 4; ++r) {
                float selA = hi ? aI[r] : aF[r];
                float selB = hi ? aG[r] : aO[r];
                float e1 = rcpf(1.f + exp2fast(selA));
                float e2 = rcpf(1.f + exp2fast(selB));
                float gg2 = fmaf(-4.f * L2E, e2, 2.f * L2E);   // 2log2e*tanh(g)
                float ig2 = e1 * gg2;                          // si*gg2 (hi only)
                h2 pk = __builtin_amdgcn_cvt_pkrtz(e1, e2);    // (F,O)  (lo only)
                unsigned uval = hi ? __builtin_bit_cast(unsigned, ig2)
                                   : *(unsigned*)&pk;
                preBx[((rl0 + r) * HLOC + hcl) * 2 + hi] = uval;  // unmasked b32
            }
        }

        // recurrence: thread = local h, 8 steps, 1 ds_read_b64 each.
        // preBx columns wave-private; same-wave LDS in-order -> no barrier.
        #pragma unroll
        for (int s = 0; s < CHUNK; ++s) {
            uint2 vv = *(const uint2*)&preBx[(s * HLOC + tid) * 2];
            h2 fo = *(h2*)&vv.x;
            float F = (float)fo.x;
            float O = (float)fo.y;
            float IG2 = __builtin_bit_cast(float, vv.y);
            cs2 = fmaf(F, cs2, IG2);
            float th = fmaf(-2.f, rcpf(1.f + exp2fast(cs2)), 1.f);
            hstate = O * th;
            op[(size_t)(ct * CHUNK + s) * (BB * HH)] = hstate;
        }
    }

    float* hout = out + (size_t)TT * BB * HH;
    float* cout = hout + (size_t)BB * HH;
    hout[(size_t)b * HH + hbase + tid] = hstate;
    cout[(size_t)b * HH + hbase + tid] = cs2 * 0.34657359027997264f; // /(2*log2e)
}

extern "C" void kernel_launch(void* const* d_in, const int* in_sizes, int n_in,
                              void* d_out, int out_size, void* d_ws, size_t ws_size,
                              hipStream_t stream) {
    const float* inputs  = (const float*)d_in[0];
    const float* centres = (const float*)d_in[1];
    const float* lin_w   = (const float*)d_in[2];
    const float* lin_b   = (const float*)d_in[3];
    float* out = (float*)d_out;

    qlstm_kernel<<<dim3(BB * 2), dim3(256), 0, stream>>>(inputs, centres, lin_w, lin_b, out);
}